// Round 2
// baseline (1411.393 us; speedup 1.0000x reference)
//
#include <hip/hip_runtime.h>
#include <cstdint>
#include <cstddef>

#define BB 256
#define TT 250
#define DIN 700
#define H1 256
#define H2 256
#define DOUT 20
#define BJ0 0.01f
#define BETAC 1.8f

// ---------------------------------------------------------------------------
// One fused transpose kernel for all 5 weight matrices (cuts launch overhead).
// ws layout (floats): wT1[700*256] | wT11[256*256] | wT12 | wT22 | wT2o[256*20]
// ---------------------------------------------------------------------------
__global__ void transpose_all_k(const float* __restrict__ w_i2h1,
                                const float* __restrict__ w_h12h1,
                                const float* __restrict__ w_h12h2,
                                const float* __restrict__ w_h22h2,
                                const float* __restrict__ w_h2o,
                                float* __restrict__ ws) {
    int i = blockIdx.x * blockDim.x + threadIdx.x;
    if (i < 179200) {                       // wT1[d*256+h] = w_i2h1[h*700+d]
        int d = i >> 8, h = i & 255;
        ws[i] = w_i2h1[h * DIN + d];
        return;
    }
    i -= 179200;
    if (i < 65536) { int d = i >> 8, h = i & 255; ws[179200 + i] = w_h12h1[h * H1 + d]; return; }
    i -= 65536;
    if (i < 65536) { int d = i >> 8, h = i & 255; ws[244736 + i] = w_h12h2[h * H1 + d]; return; }
    i -= 65536;
    if (i < 65536) { int d = i >> 8, h = i & 255; ws[310272 + i] = w_h22h2[h * H2 + d]; return; }
    i -= 65536;
    if (i < 5120)  { int j = i / 20, h = i % 20; ws[375808 + i] = w_h2o[h * H2 + j]; return; }
}

// ---------------------------------------------------------------------------
// Phase 1: Xp[t][b][h] = b_h1[h] + sum_{d: x[b,t,d]!=0} wT1[d*H1 + h]
// One wave per (b,t); lane covers h=4l..4l+3 via float4. 4-way manual unroll
// with independent accumulators for outstanding-load ILP.
// ---------------------------------------------------------------------------
__global__ __launch_bounds__(256) void xproj_k(const float* __restrict__ x,
                                               const float* __restrict__ wT1,
                                               const float* __restrict__ b_h1,
                                               float* __restrict__ Xp) {
    const int lane = threadIdx.x & 63;
    const int wv   = threadIdx.x >> 6;
    const int bt   = blockIdx.x * 4 + wv;   // grid = T*B/4 = 16000
    const int b    = bt & (BB - 1);
    const int t    = bt >> 8;

    __shared__ int lst[4][704];

    const float* xrow = x + ((size_t)b * TT + t) * DIN;
    int cnt = 0;
    for (int c = 0; c < 11; ++c) {
        int d = c * 64 + lane;
        bool p = (d < DIN) && (xrow[d] != 0.0f);
        unsigned long long m = __ballot(p ? 1 : 0);
        if (p) {
            int pos = cnt + __popcll(m & ((1ull << lane) - 1ull));
            lst[wv][pos] = d;
        }
        cnt += __popcll(m);
    }
    __syncthreads();

    float4 a0 = *(const float4*)(b_h1 + lane * 4);
    float4 a1 = {0.f, 0.f, 0.f, 0.f};
    float4 a2 = {0.f, 0.f, 0.f, 0.f};
    float4 a3 = {0.f, 0.f, 0.f, 0.f};
    int k = 0;
    for (; k + 4 <= cnt; k += 4) {
        int j0 = lst[wv][k], j1 = lst[wv][k + 1], j2 = lst[wv][k + 2], j3 = lst[wv][k + 3];
        float4 w0 = *(const float4*)(wT1 + ((size_t)j0 << 8) + lane * 4);
        float4 w1 = *(const float4*)(wT1 + ((size_t)j1 << 8) + lane * 4);
        float4 w2 = *(const float4*)(wT1 + ((size_t)j2 << 8) + lane * 4);
        float4 w3 = *(const float4*)(wT1 + ((size_t)j3 << 8) + lane * 4);
        a0.x += w0.x; a0.y += w0.y; a0.z += w0.z; a0.w += w0.w;
        a1.x += w1.x; a1.y += w1.y; a1.z += w1.z; a1.w += w1.w;
        a2.x += w2.x; a2.y += w2.y; a2.z += w2.z; a2.w += w2.w;
        a3.x += w3.x; a3.y += w3.y; a3.z += w3.z; a3.w += w3.w;
    }
    for (; k < cnt; ++k) {
        int j = lst[wv][k];
        float4 w = *(const float4*)(wT1 + ((size_t)j << 8) + lane * 4);
        a0.x += w.x; a0.y += w.y; a0.z += w.z; a0.w += w.w;
    }
    a0.x += a1.x + a2.x + a3.x;
    a0.y += a1.y + a2.y + a3.y;
    a0.z += a1.z + a2.z + a3.z;
    a0.w += a1.w + a2.w + a3.w;
    *(float4*)(Xp + ((size_t)t * BB + b) * H1 + lane * 4) = a0;
}

// ---------------------------------------------------------------------------
// Phase 2: recurrent loop. One block of 1024 threads per batch element
// (16 waves/CU vs 4 before). Thread (q = tid>>8, h = tid&255):
//   q splits each gather's k-loop 4 ways; partials combined via LDS.
// Spike lists are wave-segmented (lst[w][64] + cnt[w]) so list building
// needs no cross-wave exchange -> 4 barriers per timestep.
// Output-neuron work for step t-1 is folded into phases 1-3 of step t.
// ---------------------------------------------------------------------------
__global__ __launch_bounds__(1024) void rec_k(
    const float* __restrict__ Xp,
    const float* __restrict__ wT11, const float* __restrict__ wT12,
    const float* __restrict__ wT22, const float* __restrict__ wT2o,
    const float* __restrict__ b_h2, const float* __restrict__ b_o,
    const float* __restrict__ tau_adp_h1, const float* __restrict__ tau_adp_h2,
    const float* __restrict__ tau_m_h1, const float* __restrict__ tau_m_h2,
    const float* __restrict__ tau_m_o,
    float* __restrict__ out) {
    const int tid  = threadIdx.x;
    const int h    = tid & 255;
    const int q    = tid >> 8;        // 0..3  k-split lane
    const int b    = blockIdx.x;
    const int lane = tid & 63;
    const int wv   = tid >> 6;        // 0..15; update phase uses waves 0..3

    __shared__ int   lst1[4][64];
    __shared__ int   lst2[4][64];
    __shared__ int   cnt1[4], cnt2[4];
    __shared__ float psum1[4][256];   // reused: wT11 partials (P1), wT12 partials (P3)
    __shared__ float psumB[4][256];   // wT22 partials
    __shared__ float psumO[4][DOUT];
    __shared__ float smo[DOUT];

    float alpha1 = 0.f, ro1 = 0.f, alpha2 = 0.f, ro2 = 0.f, bh2v = 0.f;
    float mem1 = 0.f, spk1 = 0.f, bb1v = BJ0;
    float mem2 = 0.f, spk2 = 0.f, bb2v = BJ0;
    float alpo = 0.f, bov = 0.f, memo = 0.f, accs = 0.f;
    if (tid < 256) {
        alpha1 = expf(-1.0f / tau_m_h1[h]);
        ro1    = expf(-1.0f / tau_adp_h1[h]);
        alpha2 = expf(-1.0f / tau_m_h2[h]);
        ro2    = expf(-1.0f / tau_adp_h2[h]);
        bh2v   = b_h2[h];
        if (h < DOUT) { alpo = expf(-1.0f / tau_m_o[h]); bov = b_o[h]; }
    }
    if (tid < 4) { cnt1[tid] = 0; cnt2[tid] = 0; }
    __syncthreads();

    for (int t = 0; t < TT; ++t) {
        // ---- Phase 1: partial gathers over previous-step spike lists ----
        {
            float pa = 0.f, pb = 0.f;
            #pragma unroll
            for (int w = 0; w < 4; ++w) {
                const int c = cnt1[w];
                for (int k = q; k < c; k += 4) pa += wT11[((size_t)lst1[w][k] << 8) + h];
            }
            #pragma unroll
            for (int w = 0; w < 4; ++w) {
                const int c = cnt2[w];
                for (int k = q; k < c; k += 4) pb += wT22[((size_t)lst2[w][k] << 8) + h];
            }
            psum1[q][h] = pa;
            psumB[q][h] = pb;
            if (h < DOUT && t > 0) {        // output gather for step t-1
                float po = 0.f;
                #pragma unroll
                for (int w = 0; w < 4; ++w) {
                    const int c = cnt2[w];
                    for (int k = q; k < c; k += 4) po += wT2o[lst2[w][k] * DOUT + h];
                }
                psumO[q][h] = po;
            }
        }
        __syncthreads();

        // ---- Phase 2: layer-1 update (+ output memo for t-1) ----
        if (tid < 256) {
            float h1in = Xp[((size_t)t * BB + b) * H1 + h]
                       + psum1[0][h] + psum1[1][h] + psum1[2][h] + psum1[3][h];
            bb1v = ro1 * bb1v + BETAC * (1.f - ro1) * spk1;
            mem1 = mem1 * alpha1 - bb1v * spk1 + (1.f - alpha1) * h1in;
            float ns1 = (mem1 - bb1v - BJ0) > 0.f ? 1.f : 0.f;
            spk1 = ns1;
            unsigned long long m = __ballot(ns1 != 0.f ? 1 : 0);
            int pos = __popcll(m & ((1ull << lane) - 1ull));
            if (ns1 != 0.f) lst1[wv][pos] = h;
            if (lane == 0) cnt1[wv] = __popcll(m);
            if (h < DOUT && t > 0) {
                float oin = bov + psumO[0][h] + psumO[1][h] + psumO[2][h] + psumO[3][h];
                memo = memo * alpo + (1.f - alpo) * oin;
                smo[h] = memo;
            }
        }
        __syncthreads();

        // ---- Phase 3: gather wT12 over NEW lst1; softmax accum for t-1 ----
        {
            float pc = 0.f;
            #pragma unroll
            for (int w = 0; w < 4; ++w) {
                const int c = cnt1[w];
                for (int k = q; k < c; k += 4) pc += wT12[((size_t)lst1[w][k] << 8) + h];
            }
            psum1[q][h] = pc;
        }
        if (tid < DOUT && t > 0) {
            float mx = smo[0];
            for (int i = 1; i < DOUT; ++i) mx = fmaxf(mx, smo[i]);
            float s = 0.f;
            for (int i = 0; i < DOUT; ++i) s += expf(smo[i] - mx);
            accs += expf(memo - mx) / s;
        }
        __syncthreads();

        // ---- Phase 4: layer-2 update ----
        if (tid < 256) {
            float h2in = bh2v
                       + psumB[0][h] + psumB[1][h] + psumB[2][h] + psumB[3][h]
                       + psum1[0][h] + psum1[1][h] + psum1[2][h] + psum1[3][h];
            bb2v = ro2 * bb2v + BETAC * (1.f - ro2) * spk2;
            mem2 = mem2 * alpha2 - bb2v * spk2 + (1.f - alpha2) * h2in;
            float ns2 = (mem2 - bb2v - BJ0) > 0.f ? 1.f : 0.f;
            spk2 = ns2;
            unsigned long long m = __ballot(ns2 != 0.f ? 1 : 0);
            int pos = __popcll(m & ((1ull << lane) - 1ull));
            if (ns2 != 0.f) lst2[wv][pos] = h;
            if (lane == 0) cnt2[wv] = __popcll(m);
        }
        __syncthreads();
    }

    // ---- Epilogue: output neuron + softmax for the final timestep ----
    if (h < DOUT) {
        float po = 0.f;
        #pragma unroll
        for (int w = 0; w < 4; ++w) {
            const int c = cnt2[w];
            for (int k = q; k < c; k += 4) po += wT2o[lst2[w][k] * DOUT + h];
        }
        psumO[q][h] = po;
    }
    __syncthreads();
    if (tid < DOUT) {
        float oin = bov + psumO[0][h] + psumO[1][h] + psumO[2][h] + psumO[3][h];
        memo = memo * alpo + (1.f - alpo) * oin;
        smo[h] = memo;
    }
    __syncthreads();
    if (tid < DOUT) {
        float mx = smo[0];
        for (int i = 1; i < DOUT; ++i) mx = fmaxf(mx, smo[i]);
        float s = 0.f;
        for (int i = 0; i < DOUT; ++i) s += expf(smo[i] - mx);
        accs += expf(memo - mx) / s;
        out[b * DOUT + h] = accs;
    }
}

// ---------------------------------------------------------------------------
// Workspace layout (floats):
//   wT1[179200] wT11[65536] wT12[65536] wT22[65536] wT2o[5120] Xp[16384000]
// ---------------------------------------------------------------------------
extern "C" void kernel_launch(void* const* d_in, const int* in_sizes, int n_in,
                              void* d_out, int out_size, void* d_ws, size_t ws_size,
                              hipStream_t stream) {
    const float* x          = (const float*)d_in[0];
    const float* w_i2h1     = (const float*)d_in[1];
    const float* w_h12h1    = (const float*)d_in[2];
    const float* w_h12h2    = (const float*)d_in[3];
    const float* w_h22h2    = (const float*)d_in[4];
    const float* w_h2o      = (const float*)d_in[5];
    const float* b_h1       = (const float*)d_in[6];
    const float* b_h2       = (const float*)d_in[7];
    const float* b_o        = (const float*)d_in[8];
    const float* tau_adp_h1 = (const float*)d_in[9];
    const float* tau_adp_h2 = (const float*)d_in[10];
    const float* tau_m_h1   = (const float*)d_in[11];
    const float* tau_m_h2   = (const float*)d_in[12];
    const float* tau_m_o    = (const float*)d_in[13];

    float* ws   = (float*)d_ws;
    float* wT1  = ws;
    float* wT11 = wT1  + 179200;
    float* wT12 = wT11 + 65536;
    float* wT22 = wT12 + 65536;
    float* wT2o = wT22 + 65536;
    float* Xp   = wT2o + 5120;

    transpose_all_k<<<(380928 + 255) / 256, 256, 0, stream>>>(
        w_i2h1, w_h12h1, w_h12h2, w_h22h2, w_h2o, ws);

    xproj_k<<<(TT * BB) / 4, 256, 0, stream>>>(x, wT1, b_h1, Xp);

    rec_k<<<BB, 1024, 0, stream>>>(Xp, wT11, wT12, wT22, wT2o,
                                   b_h2, b_o, tau_adp_h1, tau_adp_h2,
                                   tau_m_h1, tau_m_h2, tau_m_o,
                                   (float*)d_out);
}

// Round 4
// 1138.137 us; speedup vs baseline: 1.2401x; 1.2401x over previous
//
#include <hip/hip_runtime.h>
#include <cstdint>
#include <cstddef>

#define BB 256
#define TT 250
#define DIN 700
#define H1 256
#define H2 256
#define DOUT 20
#define BJ0 0.01f
#define BETAC 1.8f

typedef float f32x4 __attribute__((ext_vector_type(4)));

// Workspace layout (floats). Every weight matrix gets one extra ZERO row so
// spike lists can be padded to a fixed batch multiple with a dummy index.
//   wT1  [701*256] @ 0        (row 700 = zeros)
//   wT11 [257*256] @ 179456   (row 256 = zeros)
//   wT12 [257*256] @ 245248
//   wT22 [257*256] @ 311040
//   wT2o [257*20 ] @ 376832   (row 256 = zeros)
//   Xp   [250*256*256] @ 381972  (16B-aligned: 381972*4 % 16 == 0)
#define OFF_WT11 179456
#define OFF_WT12 245248
#define OFF_WT22 311040
#define OFF_WT2O 376832
#define OFF_XP   381972
#define N_TRANS  381972

__global__ void transpose_all_k(const float* __restrict__ w_i2h1,
                                const float* __restrict__ w_h12h1,
                                const float* __restrict__ w_h12h2,
                                const float* __restrict__ w_h22h2,
                                const float* __restrict__ w_h2o,
                                float* __restrict__ ws) {
    int i = blockIdx.x * blockDim.x + threadIdx.x;
    if (i < 179456) { int d = i >> 8, h = i & 255;
        ws[i] = (d < DIN) ? w_i2h1[h * DIN + d] : 0.f; return; }
    i -= 179456;
    if (i < 65792) { int d = i >> 8, h = i & 255;
        ws[OFF_WT11 + i] = (d < H1) ? w_h12h1[h * H1 + d] : 0.f; return; }
    i -= 65792;
    if (i < 65792) { int d = i >> 8, h = i & 255;
        ws[OFF_WT12 + i] = (d < H1) ? w_h12h2[h * H1 + d] : 0.f; return; }
    i -= 65792;
    if (i < 65792) { int d = i >> 8, h = i & 255;
        ws[OFF_WT22 + i] = (d < H2) ? w_h22h2[h * H2 + d] : 0.f; return; }
    i -= 65792;
    if (i < 5140)  { int j = i / 20, h = i % 20;
        ws[OFF_WT2O + i] = (j < H2) ? w_h2o[h * H2 + j] : 0.f; return; }
}

// ---------------------------------------------------------------------------
// Phase 1: Xp[t][b][h] = b_h1[h] + sum_{d active} wT1[d*256 + h]
// One wave per (b,t); lane covers h=4l..4l+3 (float4). Active list padded to
// a multiple of 8 with the zero row -> 8 outstanding float4 loads per wait.
// Streaming x reads and Xp writes are nontemporal to spare L2 for weights.
// ---------------------------------------------------------------------------
__global__ __launch_bounds__(256) void xproj_k(const float* __restrict__ x,
                                               const float* __restrict__ wT1,
                                               const float* __restrict__ b_h1,
                                               float* __restrict__ Xp) {
    const int lane = threadIdx.x & 63;
    const int wv   = threadIdx.x >> 6;
    const int bt   = blockIdx.x * 4 + wv;   // grid = T*B/4 = 16000
    const int b    = bt & (BB - 1);
    const int t    = bt >> 8;

    __shared__ __align__(16) int lst[4][712];

    const float* xrow = x + ((size_t)b * TT + t) * DIN;
    int cnt = 0;
    for (int c = 0; c < 11; ++c) {
        int d = c * 64 + lane;
        bool p = false;
        if (d < DIN) p = (__builtin_nontemporal_load(xrow + d) != 0.0f);
        unsigned long long m = __ballot(p ? 1 : 0);
        if (p) {
            int pos = cnt + __popcll(m & ((1ull << lane) - 1ull));
            lst[wv][pos] = d;
        }
        cnt += __popcll(m);
    }
    int cntp = (cnt + 7) & ~7;
    if (lane < cntp - cnt) lst[wv][cnt + lane] = DIN;   // zero row pad
    __syncthreads();

    f32x4 acc0 = *(const f32x4*)(b_h1 + lane * 4);
    f32x4 acc1 = {0.f, 0.f, 0.f, 0.f};
    const int lo = lane * 4;
    for (int k = 0; k < cntp; k += 8) {
        int4 ja = *(const int4*)&lst[wv][k];
        int4 jb = *(const int4*)&lst[wv][k + 4];
        f32x4 w0 = *(const f32x4*)(wT1 + ((size_t)ja.x << 8) + lo);
        f32x4 w1 = *(const f32x4*)(wT1 + ((size_t)ja.y << 8) + lo);
        f32x4 w2 = *(const f32x4*)(wT1 + ((size_t)ja.z << 8) + lo);
        f32x4 w3 = *(const f32x4*)(wT1 + ((size_t)ja.w << 8) + lo);
        f32x4 w4 = *(const f32x4*)(wT1 + ((size_t)jb.x << 8) + lo);
        f32x4 w5 = *(const f32x4*)(wT1 + ((size_t)jb.y << 8) + lo);
        f32x4 w6 = *(const f32x4*)(wT1 + ((size_t)jb.z << 8) + lo);
        f32x4 w7 = *(const f32x4*)(wT1 + ((size_t)jb.w << 8) + lo);
        acc0 += (w0 + w1) + (w2 + w3);
        acc1 += (w4 + w5) + (w6 + w7);
    }
    acc0 += acc1;
    __builtin_nontemporal_store(acc0, (f32x4*)(Xp + ((size_t)t * BB + b) * H1 + lo));
}

// 16 gathered adds from rows lst[k..k+15] of a 256-stride table, column h.
__device__ __forceinline__ float gather16(const float* __restrict__ w,
                                          const int* lst, int k, int h) {
    int4 a = *(const int4*)(lst + k);
    int4 b = *(const int4*)(lst + k + 4);
    int4 c = *(const int4*)(lst + k + 8);
    int4 d = *(const int4*)(lst + k + 12);
    float v0  = w[((size_t)a.x << 8) + h], v1  = w[((size_t)a.y << 8) + h];
    float v2  = w[((size_t)a.z << 8) + h], v3  = w[((size_t)a.w << 8) + h];
    float v4  = w[((size_t)b.x << 8) + h], v5  = w[((size_t)b.y << 8) + h];
    float v6  = w[((size_t)b.z << 8) + h], v7  = w[((size_t)b.w << 8) + h];
    float v8  = w[((size_t)c.x << 8) + h], v9  = w[((size_t)c.y << 8) + h];
    float v10 = w[((size_t)c.z << 8) + h], v11 = w[((size_t)c.w << 8) + h];
    float v12 = w[((size_t)d.x << 8) + h], v13 = w[((size_t)d.y << 8) + h];
    float v14 = w[((size_t)d.z << 8) + h], v15 = w[((size_t)d.w << 8) + h];
    return (((v0 + v1) + (v2 + v3)) + ((v4 + v5) + (v6 + v7)))
         + (((v8 + v9) + (v10 + v11)) + ((v12 + v13) + (v14 + v15)));
}

// Same but stride-20 table (output weights).
__device__ __forceinline__ float gather16o(const float* __restrict__ w,
                                           const int* lst, int k, int h) {
    int4 a = *(const int4*)(lst + k);
    int4 b = *(const int4*)(lst + k + 4);
    int4 c = *(const int4*)(lst + k + 8);
    int4 d = *(const int4*)(lst + k + 12);
    float v0  = w[a.x * DOUT + h], v1  = w[a.y * DOUT + h];
    float v2  = w[a.z * DOUT + h], v3  = w[a.w * DOUT + h];
    float v4  = w[b.x * DOUT + h], v5  = w[b.y * DOUT + h];
    float v6  = w[b.z * DOUT + h], v7  = w[b.w * DOUT + h];
    float v8  = w[c.x * DOUT + h], v9  = w[c.y * DOUT + h];
    float v10 = w[c.z * DOUT + h], v11 = w[c.w * DOUT + h];
    float v12 = w[d.x * DOUT + h], v13 = w[d.y * DOUT + h];
    float v14 = w[d.z * DOUT + h], v15 = w[d.w * DOUT + h];
    return (((v0 + v1) + (v2 + v3)) + ((v4 + v5) + (v6 + v7)))
         + (((v8 + v9) + (v10 + v11)) + ((v12 + v13) + (v14 + v15)));
}

// ---------------------------------------------------------------------------
// Recurrent loop: one 256-thread block per batch element, thread h = neuron.
// Flat spike lists padded to multiples of 16 (zero-row dummy) -> 16+
// outstanding loads per waitcnt. 4 barriers per timestep.
// ---------------------------------------------------------------------------
__global__ __launch_bounds__(256) void rec_k(
    const float* __restrict__ Xp,
    const float* __restrict__ wT11, const float* __restrict__ wT12,
    const float* __restrict__ wT22, const float* __restrict__ wT2o,
    const float* __restrict__ b_h2, const float* __restrict__ b_o,
    const float* __restrict__ tau_adp_h1, const float* __restrict__ tau_adp_h2,
    const float* __restrict__ tau_m_h1, const float* __restrict__ tau_m_h2,
    const float* __restrict__ tau_m_o,
    float* __restrict__ out) {
    const int h    = threadIdx.x;
    const int lane = h & 63;
    const int wv   = h >> 6;
    const int b    = blockIdx.x;

    __shared__ __align__(16) int lst1[272];
    __shared__ __align__(16) int lst2[272];
    __shared__ unsigned long long wmask[4];
    __shared__ float smo[DOUT];

    const float alpha1 = expf(-1.0f / tau_m_h1[h]);
    const float ro1    = expf(-1.0f / tau_adp_h1[h]);
    const float alpha2 = expf(-1.0f / tau_m_h2[h]);
    const float ro2    = expf(-1.0f / tau_adp_h2[h]);
    const float bh2v   = b_h2[h];
    float alpo = 0.f, bov = 0.f;
    if (h < DOUT) { alpo = expf(-1.0f / tau_m_o[h]); bov = b_o[h]; }

    float mem1 = 0.f, spk1 = 0.f, bb1v = BJ0;
    float mem2 = 0.f, spk2 = 0.f, bb2v = BJ0;
    float memo = 0.f, accs = 0.f;
    int n1p = 0, n2p = 0;

    for (int t = 0; t < TT; ++t) {
        // ---- P1: prefetch Xp; gather wT11(lst1), wT22(lst2), wT2o(lst2) ----
        float xp = __builtin_nontemporal_load(Xp + ((size_t)t * BB + b) * H1 + h);
        float r1 = 0.f, r2 = 0.f, ro = 0.f;
        const bool doo = (h < DOUT) && (t > 0);
        const int kmax = n1p > n2p ? n1p : n2p;
        for (int k = 0; k < kmax; k += 16) {
            float s1 = 0.f, s2 = 0.f, s3 = 0.f;
            if (k < n1p) s1 = gather16(wT11, lst1, k, h);
            if (k < n2p) {
                s2 = gather16(wT22, lst2, k, h);
                if (doo) s3 = gather16o(wT2o, lst2, k, h);
            }
            r1 += s1; r2 += s2; ro += s3;
        }

        // ---- P2a: layer-1 update; output memo for step t-1 ----
        bb1v = ro1 * bb1v + BETAC * (1.f - ro1) * spk1;
        mem1 = mem1 * alpha1 - bb1v * spk1 + (1.f - alpha1) * (xp + r1);
        float ns1 = (mem1 - bb1v - BJ0) > 0.f ? 1.f : 0.f;
        spk1 = ns1;
        unsigned long long m1 = __ballot(ns1 != 0.f ? 1 : 0);
        if (lane == 0) wmask[wv] = m1;
        if (doo) {
            memo = memo * alpo + (1.f - alpo) * (bov + ro);
            smo[h] = memo;
        }
        __syncthreads();                               // B1

        // ---- P2b: build flat lst1 (+pad); softmax accum for t-1 ----
        {
            int pos = __popcll(m1 & ((1ull << lane) - 1ull));
            int tot = 0;
            for (int w = 0; w < 4; ++w) {
                unsigned long long mw = wmask[w];
                if (w < wv) pos += __popcll(mw);
                tot += __popcll(mw);
            }
            if (ns1 != 0.f) lst1[pos] = h;
            int np = (tot + 15) & ~15;
            if (h < np - tot) lst1[tot + h] = H1;      // zero-row pad
            n1p = np;
        }
        if (doo) {
            float mx = smo[0];
            for (int i = 1; i < DOUT; ++i) mx = fmaxf(mx, smo[i]);
            float s = 0.f;
            for (int i = 0; i < DOUT; ++i) s += expf(smo[i] - mx);
            accs += expf(memo - mx) / s;
        }
        __syncthreads();                               // B2

        // ---- P3: gather wT12 over NEW lst1 ----
        float r3 = 0.f;
        for (int k = 0; k < n1p; k += 16) r3 += gather16(wT12, lst1, k, h);

        // ---- P4a: layer-2 update ----
        bb2v = ro2 * bb2v + BETAC * (1.f - ro2) * spk2;
        mem2 = mem2 * alpha2 - bb2v * spk2 + (1.f - alpha2) * (bh2v + r2 + r3);
        float ns2 = (mem2 - bb2v - BJ0) > 0.f ? 1.f : 0.f;
        spk2 = ns2;
        unsigned long long m2 = __ballot(ns2 != 0.f ? 1 : 0);
        if (lane == 0) wmask[wv] = m2;
        __syncthreads();                               // B3

        // ---- P4b: build flat lst2 (+pad) ----
        {
            int pos = __popcll(m2 & ((1ull << lane) - 1ull));
            int tot = 0;
            for (int w = 0; w < 4; ++w) {
                unsigned long long mw = wmask[w];
                if (w < wv) pos += __popcll(mw);
                tot += __popcll(mw);
            }
            if (ns2 != 0.f) lst2[pos] = h;
            int np = (tot + 15) & ~15;
            if (h < np - tot) lst2[tot + h] = H2;      // zero-row pad
            n2p = np;
        }
        __syncthreads();                               // B4
    }

    // ---- Epilogue: output + softmax for final timestep ----
    if (h < DOUT) {
        float ro = 0.f;
        for (int k = 0; k < n2p; k += 16) ro += gather16o(wT2o, lst2, k, h);
        memo = memo * alpo + (1.f - alpo) * (bov + ro);
        smo[h] = memo;
    }
    __syncthreads();
    if (h < DOUT) {
        float mx = smo[0];
        for (int i = 1; i < DOUT; ++i) mx = fmaxf(mx, smo[i]);
        float s = 0.f;
        for (int i = 0; i < DOUT; ++i) s += expf(smo[i] - mx);
        accs += expf(memo - mx) / s;
        out[b * DOUT + h] = accs;
    }
}

extern "C" void kernel_launch(void* const* d_in, const int* in_sizes, int n_in,
                              void* d_out, int out_size, void* d_ws, size_t ws_size,
                              hipStream_t stream) {
    const float* x          = (const float*)d_in[0];
    const float* w_i2h1     = (const float*)d_in[1];
    const float* w_h12h1    = (const float*)d_in[2];
    const float* w_h12h2    = (const float*)d_in[3];
    const float* w_h22h2    = (const float*)d_in[4];
    const float* w_h2o      = (const float*)d_in[5];
    const float* b_h1       = (const float*)d_in[6];
    const float* b_h2       = (const float*)d_in[7];
    const float* b_o        = (const float*)d_in[8];
    const float* tau_adp_h1 = (const float*)d_in[9];
    const float* tau_adp_h2 = (const float*)d_in[10];
    const float* tau_m_h1   = (const float*)d_in[11];
    const float* tau_m_h2   = (const float*)d_in[12];
    const float* tau_m_o    = (const float*)d_in[13];

    float* ws   = (float*)d_ws;
    float* wT1  = ws;
    float* wT11 = ws + OFF_WT11;
    float* wT12 = ws + OFF_WT12;
    float* wT22 = ws + OFF_WT22;
    float* wT2o = ws + OFF_WT2O;
    float* Xp   = ws + OFF_XP;

    transpose_all_k<<<(N_TRANS + 255) / 256, 256, 0, stream>>>(
        w_i2h1, w_h12h1, w_h12h2, w_h22h2, w_h2o, ws);

    xproj_k<<<(TT * BB) / 4, 256, 0, stream>>>(x, wT1, b_h1, Xp);

    rec_k<<<BB, 256, 0, stream>>>(Xp, wT11, wT12, wT22, wT2o,
                                  b_h2, b_o, tau_adp_h1, tau_adp_h2,
                                  tau_m_h1, tau_m_h2, tau_m_o,
                                  (float*)d_out);
}